// Round 1
// baseline (366.641 us; speedup 1.0000x reference)
//
#include <hip/hip_runtime.h>
#include <hip/hip_bf16.h>

// e3nn FullyConnectedTensorProduct (128x0e+128x1o)^2 -> 128x0e+128x1o, N=4096
// Strategy: bf16 MFMA GEMM over K=u*v=16384 with on-the-fly A-channel generation.
// ws layout: [WT bf16 20MB][X1g bf16 4MB][X2g bf16 4MB] = ~28MB

typedef __bf16 bf16;
typedef __bf16 bf16x8 __attribute__((ext_vector_type(8)));
typedef float f32x4 __attribute__((ext_vector_type(4)));

#define WT_BYTES  (5u*4u*128u*4096u*2u)     // 20971520
#define X1_BYTES  (64u*128u*64u*4u*2u)      // 4194304
#define X2_BYTES  (4096u*4u*128u*2u)        // 4194304

__device__ __forceinline__ float blo(unsigned x){ return __uint_as_float(x << 16); }
__device__ __forceinline__ float bhi(unsigned x){ return __uint_as_float(x & 0xffff0000u); }

__device__ __forceinline__ void gl_lds16(const bf16* g, bf16* l) {
    __builtin_amdgcn_global_load_lds(
        (const __attribute__((address_space(1))) void*)g,
        (__attribute__((address_space(3))) void*)l,
        16, 0, 0);
}

// ---- prologue: weights f32 [u][v][w] -> bf16 WT[p][vb][u][w][v32], scale folded ----
__global__ __launch_bounds__(256) void pack_w_kernel(
    const float* __restrict__ w0, const float* __restrict__ w1,
    const float* __restrict__ w2, const float* __restrict__ w3,
    const float* __restrict__ w4, bf16* __restrict__ wt)
{
    __shared__ float t[32][129];
    const int b   = blockIdx.x;       // 5*128*4 = 2560
    const int p   = b >> 9;
    const int rem = b & 511;
    const int u   = rem >> 2;
    const int vb  = rem & 3;
    const float* src = (p==0)?w0:(p==1)?w1:(p==2)?w2:(p==3)?w3:w4;
    const float scale = (p==0)?1.0f:(p==4)?0.40824829046386302f:0.57735026918962576f;

    const float* sp = src + (size_t)u*16384 + (size_t)vb*4096; // [vi][w] rows of 128
    for (int e = threadIdx.x; e < 32*128; e += 256) {
        const int vi = e >> 7, w = e & 127;
        t[vi][w] = sp[e];
    }
    __syncthreads();
    bf16* op = wt + (size_t)((p*4 + vb)*128 + u)*4096;
    for (int e = threadIdx.x; e < 4096; e += 256) {
        const int w = e >> 5, vi = e & 31;
        op[e] = (bf16)(t[vi][w] * scale);
    }
}

// ---- prologue: pack x1 -> [tile][u][node][q] bf16 ; x2 -> [node][q][v] bf16 ----
__global__ __launch_bounds__(256) void pack_x_kernel(
    const float* __restrict__ x1s, const float* __restrict__ x1v,
    const float* __restrict__ x2s, const float* __restrict__ x2v,
    bf16* __restrict__ x1g, bf16* __restrict__ x2g)
{
    const int tid = blockIdx.x*256 + threadIdx.x;
    if (blockIdx.x < 2048) {
        const int n = tid & 4095, u = tid >> 12;
        const int t = n >> 6, nd = n & 63;
        const size_t o = ((size_t)(t*128 + u)*64 + nd) * 4;
        const size_t i = (size_t)n*128 + u;
        x1g[o+0] = (bf16)x1s[i];
        x1g[o+1] = (bf16)x1v[i*3 + 0];
        x1g[o+2] = (bf16)x1v[i*3 + 1];
        x1g[o+3] = (bf16)x1v[i*3 + 2];
    } else {
        const int tt = tid - 2048*256;
        const int n = tt >> 7, v = tt & 127;
        const size_t b = (size_t)n*512;
        const size_t i = (size_t)n*128 + v;
        x2g[b +   0 + v] = (bf16)x2s[i];
        x2g[b + 128 + v] = (bf16)x2v[i*3 + 0];
        x2g[b + 256 + v] = (bf16)x2v[i*3 + 1];
        x2g[b + 384 + v] = (bf16)x2v[i*3 + 2];
    }
}

// ---- main: 256 WGs = 64 node-tiles x 4 u-sections, 512 thr (8 waves) ----
// wave = (rgroup 0..1, cgroup 0..3): 2 row-tiles(16 nodes) x 2 col-tiles(16 w)
__global__ __launch_bounds__(512, 2) void tp_main(
    const bf16* __restrict__ wt, const bf16* __restrict__ x1g,
    const bf16* __restrict__ x2g, float* __restrict__ out)
{
    __shared__ __align__(16) bf16 wlds[2*5*4096];   // 80 KB: dbuf x 5 paths x [128w][32v]
    __shared__ __align__(16) bf16 x1lds[32*64*4];   // 16 KB: [urel][node][q]

    const int tid    = threadIdx.x;
    const int lane   = tid & 63;
    const int wv     = tid >> 6;
    const int rgroup = wv >> 2;
    const int cgroup = wv & 3;
    const int kg     = lane >> 4;
    const int lr     = lane & 15;

    const int tile = blockIdx.x >> 2;
    const int uoff = (blockIdx.x & 3) * 32;

    // weight-staging lane constants: lane l covers row swrow, 16B chunk (l&3).
    // Source chunk swizzled (q = pc ^ s(w)) so B-frag ds_reads are ~2-way only.
    const int swrow   = wv*16 + (lane>>2);
    const int sq      = (lane&3) ^ ((swrow>>1)&3);
    const int s_eloff = swrow*32 + sq*8;

    int boff[2];
    #pragma unroll
    for (int ct = 0; ct < 2; ++ct) {
        const int wcol = cgroup*32 + ct*16 + lr;
        boff[ct] = wcol*32 + ((kg ^ ((wcol>>1)&3))*8);
    }

    // stage x1 slice (16 KB) + weight chunk 0
    {
        const bf16* s = x1g + (size_t)tile*32768 + (size_t)uoff*256;
        gl_lds16(s + (wv*2+0)*512 + lane*8, x1lds + (wv*2+0)*512);
        gl_lds16(s + (wv*2+1)*512 + lane*8, x1lds + (wv*2+1)*512);
    }
    {
        const bf16* cb = wt + (size_t)uoff*4096 + s_eloff;   // vb=0,u=uoff
        bf16* lb = wlds + wv*512;
        #pragma unroll
        for (int p = 0; p < 5; ++p)
            gl_lds16(cb + (size_t)p*2097152, lb + p*4096);
    }
    __syncthreads();

    f32x4 acc[2][2][4];
    #pragma unroll
    for (int a = 0; a < 2; ++a)
        #pragma unroll
        for (int b = 0; b < 2; ++b)
            #pragma unroll
            for (int d = 0; d < 4; ++d)
                acc[a][b][d] = (f32x4){0.f, 0.f, 0.f, 0.f};

    float x2f[2][4][8];

    for (int c = 0; c < 128; ++c) {
        const int urel = c & 31;
        const int nb   = c & 1;

        if (urel == 0) {   // refresh x2 register slices for this v-block
            const int vb = c >> 5;
            #pragma unroll
            for (int rt = 0; rt < 2; ++rt) {
                const int n = tile*64 + rgroup*32 + rt*16 + lr;
                #pragma unroll
                for (int q = 0; q < 4; ++q) {
                    const uint4 h = *(const uint4*)(x2g + (size_t)(n*4 + q)*128 + vb*32 + kg*8);
                    x2f[rt][q][0]=blo(h.x); x2f[rt][q][1]=bhi(h.x);
                    x2f[rt][q][2]=blo(h.y); x2f[rt][q][3]=bhi(h.y);
                    x2f[rt][q][4]=blo(h.z); x2f[rt][q][5]=bhi(h.z);
                    x2f[rt][q][6]=blo(h.w); x2f[rt][q][7]=bhi(h.w);
                }
            }
        }

        if (c + 1 < 128) {   // stage next chunk into other buffer
            const int c1 = c + 1;
            const bf16* cb = wt + (size_t)((c1>>5)*128 + uoff + (c1&31))*4096 + s_eloff;
            bf16* lb = wlds + (c1&1)*20480 + wv*512;
            #pragma unroll
            for (int p = 0; p < 5; ++p)
                gl_lds16(cb + (size_t)p*2097152, lb + p*4096);
        }

        // B fragments (5 weights x 2 col-tiles)
        bf16x8 bfr[5][2];
        const bf16* wb = wlds + nb*20480;
        #pragma unroll
        for (int p = 0; p < 5; ++p)
            #pragma unroll
            for (int ct = 0; ct < 2; ++ct)
                bfr[p][ct] = *(const bf16x8*)(wb + p*4096 + boff[ct]);

        #pragma unroll
        for (int rt = 0; rt < 2; ++rt) {
            const int nodel = rgroup*32 + rt*16 + lr;
            const uint2 h1 = *(const uint2*)(x1lds + urel*256 + nodel*4);
            const float s1  = blo(h1.x), v1x = bhi(h1.x);
            const float v1y = blo(h1.y), v1z = bhi(h1.y);

            bf16x8 a_sss, a_vvs, a_sv0, a_sv1, a_sv2, a_vs0, a_vs1, a_vs2, a_x0, a_x1, a_x2;
            #pragma unroll
            for (int i = 0; i < 8; ++i) {
                const float s2 = x2f[rt][0][i];
                const float vx = x2f[rt][1][i];
                const float vy = x2f[rt][2][i];
                const float vz = x2f[rt][3][i];
                a_sss[i] = (bf16)(s1*s2);
                a_vvs[i] = (bf16)(v1x*vx + v1y*vy + v1z*vz);
                a_sv0[i] = (bf16)(s1*vx);
                a_sv1[i] = (bf16)(s1*vy);
                a_sv2[i] = (bf16)(s1*vz);
                a_vs0[i] = (bf16)(v1x*s2);
                a_vs1[i] = (bf16)(v1y*s2);
                a_vs2[i] = (bf16)(v1z*s2);
                a_x0[i]  = (bf16)(v1y*vz - v1z*vy);
                a_x1[i]  = (bf16)(v1z*vx - v1x*vz);
                a_x2[i]  = (bf16)(v1x*vy - v1y*vx);
            }
            #pragma unroll
            for (int ct = 0; ct < 2; ++ct) {
                acc[rt][ct][0] = __builtin_amdgcn_mfma_f32_16x16x32_bf16(a_sss, bfr[0][ct], acc[rt][ct][0], 0,0,0);
                acc[rt][ct][0] = __builtin_amdgcn_mfma_f32_16x16x32_bf16(a_vvs, bfr[1][ct], acc[rt][ct][0], 0,0,0);
                acc[rt][ct][1] = __builtin_amdgcn_mfma_f32_16x16x32_bf16(a_sv0, bfr[2][ct], acc[rt][ct][1], 0,0,0);
                acc[rt][ct][1] = __builtin_amdgcn_mfma_f32_16x16x32_bf16(a_vs0, bfr[3][ct], acc[rt][ct][1], 0,0,0);
                acc[rt][ct][1] = __builtin_amdgcn_mfma_f32_16x16x32_bf16(a_x0,  bfr[4][ct], acc[rt][ct][1], 0,0,0);
                acc[rt][ct][2] = __builtin_amdgcn_mfma_f32_16x16x32_bf16(a_sv1, bfr[2][ct], acc[rt][ct][2], 0,0,0);
                acc[rt][ct][2] = __builtin_amdgcn_mfma_f32_16x16x32_bf16(a_vs1, bfr[3][ct], acc[rt][ct][2], 0,0,0);
                acc[rt][ct][2] = __builtin_amdgcn_mfma_f32_16x16x32_bf16(a_x1,  bfr[4][ct], acc[rt][ct][2], 0,0,0);
                acc[rt][ct][3] = __builtin_amdgcn_mfma_f32_16x16x32_bf16(a_sv2, bfr[2][ct], acc[rt][ct][3], 0,0,0);
                acc[rt][ct][3] = __builtin_amdgcn_mfma_f32_16x16x32_bf16(a_vs2, bfr[3][ct], acc[rt][ct][3], 0,0,0);
                acc[rt][ct][3] = __builtin_amdgcn_mfma_f32_16x16x32_bf16(a_x2,  bfr[4][ct], acc[rt][ct][3], 0,0,0);
            }
        }
        __syncthreads();
    }

    // epilogue: accumulate K-split partials into d_out
    #pragma unroll
    for (int rt = 0; rt < 2; ++rt) {
        #pragma unroll
        for (int ct = 0; ct < 2; ++ct) {
            const int w = cgroup*32 + ct*16 + lr;
            #pragma unroll
            for (int j = 0; j < 4; ++j) {
                const int n = tile*64 + rgroup*32 + rt*16 + kg*4 + j;
                float* op = out + (size_t)n*512;
                unsafeAtomicAdd(op + w,             acc[rt][ct][0][j]);
                unsafeAtomicAdd(op + 128 + w*3 + 0, acc[rt][ct][1][j]);
                unsafeAtomicAdd(op + 128 + w*3 + 1, acc[rt][ct][2][j]);
                unsafeAtomicAdd(op + 128 + w*3 + 2, acc[rt][ct][3][j]);
            }
        }
    }
}

extern "C" void kernel_launch(void* const* d_in, const int* in_sizes, int n_in,
                              void* d_out, int out_size, void* d_ws, size_t ws_size,
                              hipStream_t stream)
{
    const float* x1s = (const float*)d_in[0];
    const float* x1v = (const float*)d_in[1];
    const float* x2s = (const float*)d_in[2];
    const float* x2v = (const float*)d_in[3];
    const float* w0  = (const float*)d_in[4];
    const float* w1  = (const float*)d_in[5];
    const float* w2  = (const float*)d_in[6];
    const float* w3  = (const float*)d_in[7];
    const float* w4  = (const float*)d_in[8];

    bf16* wtb = (bf16*)d_ws;
    bf16* x1g = (bf16*)((char*)d_ws + WT_BYTES);
    bf16* x2g = (bf16*)((char*)d_ws + WT_BYTES + X1_BYTES);
    float* out = (float*)d_out;

    pack_w_kernel<<<2560, 256, 0, stream>>>(w0, w1, w2, w3, w4, wtb);
    pack_x_kernel<<<4096, 256, 0, stream>>>(x1s, x1v, x2s, x2v, x1g, x2g);
    hipMemsetAsync(d_out, 0, (size_t)out_size*sizeof(float), stream);
    tp_main<<<256, 512, 0, stream>>>(wtb, x1g, x2g, out);
}

// Round 2
// 318.437 us; speedup vs baseline: 1.1514x; 1.1514x over previous
//
#include <hip/hip_runtime.h>
#include <hip/hip_bf16.h>

// e3nn FullyConnectedTensorProduct (128x0e+128x1o)^2 -> 128x0e+128x1o, N=4096
// R2: L2-resident weight slices (XCD-aware placement), 256n x 32w WG tiles
//     (4x less weight traffic), f32x2 packed A-gen + asm v_cvt_pk_bf16_f32.
// ws layout: [WT bf16 20MB][X1g bf16 4MB][X2g bf16 4MB]

typedef __bf16 bf16;
typedef __bf16 bf16x8 __attribute__((ext_vector_type(8)));
typedef float f32x4 __attribute__((ext_vector_type(4)));
typedef float f32x2 __attribute__((ext_vector_type(2)));
typedef unsigned u32;

#define WT_BYTES  (5u*4u*128u*4096u*2u)     // 20971520 (5 paths x 128u x 4vb x 4wsec x 1024 el x 2B)
#define X1_BYTES  (16u*4u*32768u*2u)        // 4194304  ([tile16][usec4][u32][n256][q4] bf16)

__device__ __forceinline__ float blo(u32 x){ return __uint_as_float(x << 16); }
__device__ __forceinline__ float bhi(u32 x){ return __uint_as_float(x & 0xffff0000u); }

__device__ __forceinline__ u32 cvtpk(float lo, float hi){
    u32 r;
    asm("v_cvt_pk_bf16_f32 %0, %1, %2" : "=v"(r) : "v"(lo), "v"(hi));
    return r;
}

union Frag { u32 u[4]; bf16x8 v; };
__device__ __forceinline__ bf16x8 FR(const u32 a[4]){
    Frag f; f.u[0]=a[0]; f.u[1]=a[1]; f.u[2]=a[2]; f.u[3]=a[3]; return f.v;
}
__device__ __forceinline__ f32x2 sp(float s){ return (f32x2){s, s}; }

__device__ __forceinline__ void gl_lds16(const bf16* g, bf16* l) {
    __builtin_amdgcn_global_load_lds(
        (const __attribute__((address_space(1))) void*)g,
        (__attribute__((address_space(3))) void*)l,
        16, 0, 0);
}

// ---- prologue: weights f32 [u][v][w] -> bf16 WT[p][u][vb][wsec][32w][4chunk-swz][8v] ----
__global__ __launch_bounds__(256) void pack_w_kernel(
    const float* __restrict__ w0, const float* __restrict__ w1,
    const float* __restrict__ w2, const float* __restrict__ w3,
    const float* __restrict__ w4, bf16* __restrict__ wt)
{
    __shared__ float tl[64][130];
    const int b = blockIdx.x;           // 640 = 5 paths x 128 u
    const int p = b >> 7;
    const int u = b & 127;
    const float* src = (p==0)?w0:(p==1)?w1:(p==2)?w2:(p==3)?w3:w4;
    const float scale = (p==0)?1.0f:(p==4)?0.40824829046386302f:0.57735026918962576f;

    for (int h = 0; h < 2; ++h) {       // two 64-v halves
        const float* spR = src + (size_t)u*16384 + (size_t)h*8192;
        #pragma unroll
        for (int k = 0; k < 8; ++k) {
            const int e4 = (k*256 + threadIdx.x) * 4;
            const float4 v4 = *(const float4*)(spR + e4);
            const int vi = e4 >> 7, w = e4 & 127;
            tl[vi][w+0]=v4.x; tl[vi][w+1]=v4.y; tl[vi][w+2]=v4.z; tl[vi][w+3]=v4.w;
        }
        __syncthreads();
        #pragma unroll
        for (int k = 0; k < 4; ++k) {
            const int cid = k*256 + threadIdx.x;     // 0..1023 chunks of 16B
            const int vbh  = cid >> 9;
            const int wsec = (cid >> 7) & 3;
            const int w    = (cid >> 2) & 31;
            const int q    = cid & 3;
            const int vb   = h*2 + vbh;
            const int qs   = q ^ ((w >> 1) & 3);
            bf16x8 t8;
            #pragma unroll
            for (int j = 0; j < 8; ++j)
                t8[j] = (bf16)(tl[vbh*32 + q*8 + j][wsec*32 + w] * scale);
            *(bf16x8*)(wt + ((size_t)(((p*128 + u)*4 + vb)*4 + wsec) << 10) + w*32 + qs*8) = t8;
        }
        __syncthreads();
    }
}

// ---- prologue: pack x1 -> [tile][usec][u32][n256][q4]; x2 -> [n][q][v] bf16 ----
__global__ __launch_bounds__(256) void pack_x_kernel(
    const float* __restrict__ x1s, const float* __restrict__ x1v,
    const float* __restrict__ x2s, const float* __restrict__ x2v,
    bf16* __restrict__ x1g, bf16* __restrict__ x2g)
{
    if (blockIdx.x < 128) {
        // 32 nodes x 128 u per block, LDS transpose for coalesced R+W
        __shared__ uint2 tl[128][33];
        const int nb = blockIdx.x;
        #pragma unroll
        for (int k = 0; k < 16; ++k) {
            const int idx = k*256 + threadIdx.x;    // 0..4095, u fast
            const int u = idx & 127, nd = idx >> 7;
            const size_t i = (size_t)(nb*32 + nd)*128 + u;
            union { bf16 h[4]; uint2 u2; } tp;
            tp.h[0] = (bf16)x1s[i];
            tp.h[1] = (bf16)x1v[i*3 + 0];
            tp.h[2] = (bf16)x1v[i*3 + 1];
            tp.h[3] = (bf16)x1v[i*3 + 2];
            tl[u][nd] = tp.u2;
        }
        __syncthreads();
        uint2* og = (uint2*)x1g;
        const int t = nb >> 3, nd0 = (nb & 7) * 32;
        #pragma unroll
        for (int k = 0; k < 16; ++k) {
            const int idx = k*256 + threadIdx.x;    // nd fast
            const int u = idx >> 5, nd = idx & 31;
            og[(((t*4 + (u>>5))*32 + (u&31)) << 8) + nd0 + nd] = tl[u][nd];
        }
    } else {
        const int tt = (blockIdx.x - 128)*256 + threadIdx.x;  // 0..524287
        const int n = tt >> 7, v = tt & 127;
        const size_t b = (size_t)n*512;
        const size_t i = (size_t)n*128 + v;
        x2g[b +   0 + v] = (bf16)x2s[i];
        x2g[b + 128 + v] = (bf16)x2v[i*3 + 0];
        x2g[b + 256 + v] = (bf16)x2v[i*3 + 1];
        x2g[b + 384 + v] = (bf16)x2v[i*3 + 2];
    }
}

// stage one K-chunk (10KB = 5 paths x [32w][32v] pre-swizzled) into LDS buffer
__device__ __forceinline__ void stage_chunk(const bf16* __restrict__ wt, bf16* dst,
                                            int u, int vb, int wsec, int wv, int lane)
{
    {
        const int e = wv, p = e >> 1, h = e & 1;
        gl_lds16(wt + ((size_t)(((p*128 + u)*4 + vb)*4 + wsec) << 10) + (h<<9) + lane*8,
                 dst + (e<<9));
    }
    if (wv < 2) {
        const int e = wv + 8, p = e >> 1, h = e & 1;
        gl_lds16(wt + ((size_t)(((p*128 + u)*4 + vb)*4 + wsec) << 10) + (h<<9) + lane*8,
                 dst + (e<<9));
    }
}

// ---- main: 256 WGs = 16 node-tiles(256) x 4 u-sec x 4 w-sec, 512 thr ----
// XCD-aware: blockIdx&7 = XCD hosts 2 weight slices (2.5MB, L2-resident).
// wave = one 32-node group; covers 32n x 32w (2 rt x 2 ct MFMA tiles).
__global__ __launch_bounds__(512, 2) void tp_main(
    const bf16* __restrict__ wt, const bf16* __restrict__ x1g,
    const bf16* __restrict__ x2g, float* __restrict__ out)
{
    __shared__ __align__(16) bf16 wlds[2*5120];   // 20 KB dbuf weights
    __shared__ __align__(16) bf16 x1lds[32768];   // 64 KB x1 slice [u32][n256][q4]

    const int tid  = threadIdx.x;
    const int lane = tid & 63;
    const int wv   = tid >> 6;
    const int kg   = lane >> 4;
    const int lr   = lane & 15;

    const int b    = blockIdx.x;
    const int s    = (b & 7)*2 + ((b >> 3) & 1);  // weight slice 0..15
    const int t    = b >> 4;                      // node tile 0..15
    const int usec = s >> 2;
    const int wsec = s & 3;

    int boff[2];
    #pragma unroll
    for (int ct = 0; ct < 2; ++ct) {
        const int wp = ct*16 + lr;                // w row within 32-tile
        boff[ct] = wp*32 + ((kg ^ ((wp >> 1) & 3)) * 8);
    }

    // stage x1 slice (64KB) + weight chunk 0
    {
        const bf16* src = x1g + ((size_t)(t*4 + usec) << 15);
        #pragma unroll
        for (int r = 0; r < 8; ++r)
            gl_lds16(src + (wv*8 + r)*512 + lane*8, x1lds + (wv*8 + r)*512);
    }
    stage_chunk(wt, wlds, usec*32, 0, wsec, wv, lane);
    __syncthreads();

    f32x4 acc[2][2][4];
    #pragma unroll
    for (int a = 0; a < 2; ++a)
        #pragma unroll
        for (int c2 = 0; c2 < 2; ++c2)
            #pragma unroll
            for (int d = 0; d < 4; ++d)
                acc[a][c2][d] = (f32x4){0.f, 0.f, 0.f, 0.f};

    f32x2 xp[2][4][4];   // [rt][q][vpair]

    for (int c = 0; c < 128; ++c) {
        const int urel = c & 31;
        const int nb   = c & 1;

        if (urel == 0) {   // refresh x2 register slices for this v-block
            const int vb = c >> 5;
            #pragma unroll
            for (int rt = 0; rt < 2; ++rt) {
                const int n = t*256 + wv*32 + rt*16 + lr;
                #pragma unroll
                for (int q = 0; q < 4; ++q) {
                    const uint4 h = *(const uint4*)(x2g + ((size_t)(n*4 + q) << 7) + vb*32 + kg*8);
                    xp[rt][q][0] = (f32x2){blo(h.x), bhi(h.x)};
                    xp[rt][q][1] = (f32x2){blo(h.y), bhi(h.y)};
                    xp[rt][q][2] = (f32x2){blo(h.z), bhi(h.z)};
                    xp[rt][q][3] = (f32x2){blo(h.w), bhi(h.w)};
                }
            }
        }

        if (c + 1 < 128)
            stage_chunk(wt, wlds + (nb^1)*5120, usec*32 + ((c+1) & 31), (c+1) >> 5, wsec, wv, lane);

        // B fragments (5 paths x 2 col-tiles)
        bf16x8 bfr[5][2];
        const bf16* wb = wlds + nb*5120;
        #pragma unroll
        for (int p = 0; p < 5; ++p)
            #pragma unroll
            for (int ct = 0; ct < 2; ++ct)
                bfr[p][ct] = *(const bf16x8*)(wb + p*1024 + boff[ct]);

        #pragma unroll
        for (int rt = 0; rt < 2; ++rt) {
            const int nodel = wv*32 + rt*16 + lr;
            const uint2 h1 = *(const uint2*)(x1lds + urel*1024 + nodel*4);
            const float s1 = blo(h1.x);
            float v1a[3];
            v1a[0] = bhi(h1.x); v1a[1] = blo(h1.y); v1a[2] = bhi(h1.y);

            // ---- scalar-output channels: sss, vvs ----
            {
                u32 f0[4], f1[4];
                #pragma unroll
                for (int j = 0; j < 4; ++j) {
                    const f32x2 s2 = xp[rt][0][j];
                    const f32x2 vx = xp[rt][1][j], vy = xp[rt][2][j], vz = xp[rt][3][j];
                    const f32x2 cs = sp(s1)*s2;
                    const f32x2 cd = sp(v1a[0])*vx + sp(v1a[1])*vy + sp(v1a[2])*vz;
                    f0[j] = cvtpk(cs.x, cs.y);
                    f1[j] = cvtpk(cd.x, cd.y);
                }
                #pragma unroll
                for (int ct = 0; ct < 2; ++ct) {
                    acc[rt][ct][0] = __builtin_amdgcn_mfma_f32_16x16x32_bf16(FR(f0), bfr[0][ct], acc[rt][ct][0], 0,0,0);
                    acc[rt][ct][0] = __builtin_amdgcn_mfma_f32_16x16x32_bf16(FR(f1), bfr[1][ct], acc[rt][ct][0], 0,0,0);
                }
            }
            // ---- vector-output channels per component k: svv, vsv, vvv(cross) ----
            #pragma unroll
            for (int k = 0; k < 3; ++k) {
                const int k1 = (k+1) % 3, k2 = (k+2) % 3;
                u32 fa[4], fb[4], fc[4];
                #pragma unroll
                for (int j = 0; j < 4; ++j) {
                    const f32x2 s2 = xp[rt][0][j];
                    const f32x2 vk  = xp[rt][1+k][j];
                    const f32x2 vk1 = xp[rt][1+k1][j];
                    const f32x2 vk2 = xp[rt][1+k2][j];
                    const f32x2 c_sv = sp(s1)    * vk;
                    const f32x2 c_vs = sp(v1a[k])* s2;
                    const f32x2 c_x  = sp(v1a[k1])*vk2 - sp(v1a[k2])*vk1;
                    fa[j] = cvtpk(c_sv.x, c_sv.y);
                    fb[j] = cvtpk(c_vs.x, c_vs.y);
                    fc[j] = cvtpk(c_x.x,  c_x.y);
                }
                #pragma unroll
                for (int ct = 0; ct < 2; ++ct) {
                    acc[rt][ct][1+k] = __builtin_amdgcn_mfma_f32_16x16x32_bf16(FR(fa), bfr[2][ct], acc[rt][ct][1+k], 0,0,0);
                    acc[rt][ct][1+k] = __builtin_amdgcn_mfma_f32_16x16x32_bf16(FR(fb), bfr[3][ct], acc[rt][ct][1+k], 0,0,0);
                    acc[rt][ct][1+k] = __builtin_amdgcn_mfma_f32_16x16x32_bf16(FR(fc), bfr[4][ct], acc[rt][ct][1+k], 0,0,0);
                }
            }
        }
        __syncthreads();
    }

    // epilogue: accumulate u-section partials into d_out (4 contributors/elem)
    #pragma unroll
    for (int rt = 0; rt < 2; ++rt) {
        #pragma unroll
        for (int ct = 0; ct < 2; ++ct) {
            const int w = wsec*32 + ct*16 + lr;
            #pragma unroll
            for (int j = 0; j < 4; ++j) {
                const int n = t*256 + wv*32 + rt*16 + kg*4 + j;
                float* op = out + (size_t)n*512;
                unsafeAtomicAdd(op + w,             acc[rt][ct][0][j]);
                unsafeAtomicAdd(op + 128 + w*3 + 0, acc[rt][ct][1][j]);
                unsafeAtomicAdd(op + 128 + w*3 + 1, acc[rt][ct][2][j]);
                unsafeAtomicAdd(op + 128 + w*3 + 2, acc[rt][ct][3][j]);
            }
        }
    }
}

extern "C" void kernel_launch(void* const* d_in, const int* in_sizes, int n_in,
                              void* d_out, int out_size, void* d_ws, size_t ws_size,
                              hipStream_t stream)
{
    const float* x1s = (const float*)d_in[0];
    const float* x1v = (const float*)d_in[1];
    const float* x2s = (const float*)d_in[2];
    const float* x2v = (const float*)d_in[3];
    const float* w0  = (const float*)d_in[4];
    const float* w1  = (const float*)d_in[5];
    const float* w2  = (const float*)d_in[6];
    const float* w3  = (const float*)d_in[7];
    const float* w4  = (const float*)d_in[8];

    bf16* wtb = (bf16*)d_ws;
    bf16* x1g = (bf16*)((char*)d_ws + WT_BYTES);
    bf16* x2g = (bf16*)((char*)d_ws + WT_BYTES + X1_BYTES);
    float* out = (float*)d_out;

    pack_w_kernel<<<640, 256, 0, stream>>>(w0, w1, w2, w3, w4, wtb);
    pack_x_kernel<<<2176, 256, 0, stream>>>(x1s, x1v, x2s, x2v, x1g, x2g);
    hipMemsetAsync(d_out, 0, (size_t)out_size*sizeof(float), stream);
    tp_main<<<256, 512, 0, stream>>>(wtb, x1g, x2g, out);
}